// Round 2
// baseline (306.542 us; speedup 1.0000x reference)
//
#include <hip/hip_runtime.h>
#include <stdint.h>

#define BH 32
#define LSEQ 4096
#define DDIM 128
#define CHUNKS 16
#define CHUNK_ROWS 256
#define STATE_SZ (DDIM*DDIM + DDIM)   // 16512 floats per (bh, chunk), [d][e] then Z[d]

typedef __attribute__((ext_vector_type(8))) short bf16x8;
typedef __attribute__((ext_vector_type(4))) float f32x4;

__device__ inline uint16_t f2bf(float f) {
    uint32_t x = __builtin_bit_cast(uint32_t, f);
    x += 0x7fffu + ((x >> 16) & 1u);
    return (uint16_t)(x >> 16);
}
__device__ inline uint32_t pack2(float a, float b) {
    return (uint32_t)f2bf(a) | ((uint32_t)f2bf(b) << 16);
}
// phi(x) = clip(elu(x*s+b)+1, 0, 10)
__device__ inline float phi_f(float x, float s, float b) {
    float y = fmaf(x, s, b);
    float pos = fminf(y + 1.0f, 10.0f);
    float neg = __expf(y);
    return (y > 0.0f) ? pos : neg;
}
// LDS-only barrier drain: keeps global prefetch loads in flight across barriers.
// All cross-wave communication in these kernels is through LDS.
__device__ inline void bar_lgkm() {
    asm volatile("s_waitcnt lgkmcnt(0)\n\ts_barrier" ::: "memory");
}

// =====================================================================
// P1: per-chunk state totals  S_c = phi_K_c^T @ V_c  (K=256), Z_c
// LDS: pk bufs 2x16KB @0, vT bufs 2x16KB @32768, Zpart @65536 (2KB)
#define SMEM1 67584
__global__ __launch_bounds__(512, 4) void la_state(
    const float* __restrict__ K, const float* __restrict__ V,
    const float* __restrict__ scale, const float* __restrict__ bias,
    float* __restrict__ states)
{
    extern __shared__ char smem[];
    const int tid  = threadIdx.x;
    const int bh   = blockIdx.x >> 4;
    const int ch   = blockIdx.x & 15;
    const int h    = bh & 15;
    const int lane = tid & 63;
    const int wid  = tid >> 6;
    const int i15  = lane & 15;
    const int q4   = lane >> 4;
    const size_t base = (size_t)bh * LSEQ * DDIM;
    const int row0 = ch * CHUNK_ROWS;

    const int d  = tid & 127;      // column this thread stages (both K->pkT and V->vT)
    const int rg = tid >> 7;       // 0..3 -> local rows 16rg..16rg+15 of a 64-row granule
    const float sk = scale[h*DDIM + d];
    const float bk = bias [h*DDIM + d];

    f32x4 accS[8];
    #pragma unroll
    for (int mt = 0; mt < 8; ++mt) accS[mt] = (f32x4){0.f,0.f,0.f,0.f};
    float zacc = 0.f;

    float kreg[16], vreg[16];
    auto load_kv = [&](int g) {
        const float* Kc = K + base + (size_t)(row0 + 64*g + 16*rg)*DDIM + d;
        const float* Vc = V + base + (size_t)(row0 + 64*g + 16*rg)*DDIM + d;
        #pragma unroll
        for (int j = 0; j < 16; ++j) {
            kreg[j] = Kc[(size_t)j*DDIM];
            vreg[j] = Vc[(size_t)j*DDIM];
        }
    };
    auto stage = [&](int b) {   // phi/pack current regs -> buf b (transposed layout [col][r])
        uint32_t wk[8], wv8[8];
        #pragma unroll
        for (int j = 0; j < 8; ++j) {
            float p0 = phi_f(kreg[2*j],   sk, bk);
            float p1 = phi_f(kreg[2*j+1], sk, bk);
            zacc += p0 + p1;
            wk[j]  = pack2(p0, p1);
            wv8[j] = pack2(vreg[2*j], vreg[2*j+1]);
        }
        char* pkb = smem + b*16384;
        char* vtb = smem + 32768 + b*16384;
        const uint32_t lin = (uint32_t)(d*128 + 32*rg);
        const uint32_t swz = (uint32_t)((d & 7) << 4);
        *(uint4*)(pkb + ((lin     ) ^ swz)) = ((const uint4*)wk)[0];
        *(uint4*)(pkb + ((lin + 16) ^ swz)) = ((const uint4*)wk)[1];
        *(uint4*)(vtb + ((lin     ) ^ swz)) = ((const uint4*)wv8)[0];
        *(uint4*)(vtb + ((lin + 16) ^ swz)) = ((const uint4*)wv8)[1];
    };

    load_kv(0);
    stage(0);
    load_kv(1);
    bar_lgkm();

    #pragma unroll
    for (int g = 0; g < 4; ++g) {
        if (g < 3) stage((g+1)&1);
        if (g < 2) load_kv(g+2);
        const char* pkb = smem + (g&1)*16384;
        const char* vtb = smem + 32768 + (g&1)*16384;
        const uint32_t swz = (uint32_t)((i15 & 7) << 4);
        #pragma unroll
        for (int ksl = 0; ksl < 2; ++ksl) {
            bf16x8 bv = *(const bf16x8*)(vtb + (((uint32_t)((16*wid+i15)*128 + 64*ksl + 16*q4)) ^ swz));
            #pragma unroll
            for (int mt = 0; mt < 8; ++mt) {
                bf16x8 av = *(const bf16x8*)(pkb + (((uint32_t)((16*mt+i15)*128 + 64*ksl + 16*q4)) ^ swz));
                accS[mt] = __builtin_amdgcn_mfma_f32_16x16x32_bf16(av, bv, accS[mt], 0, 0, 0);
            }
        }
        bar_lgkm();
    }

    float* Zpart = (float*)(smem + 65536);
    Zpart[rg*128 + d] = zacc;
    float* stb = states + (size_t)(bh*CHUNKS + ch)*STATE_SZ;
    #pragma unroll
    for (int mt = 0; mt < 8; ++mt)
        #pragma unroll
        for (int r = 0; r < 4; ++r)
            stb[(size_t)(16*mt + 4*q4 + r)*DDIM + 16*wid + i15] = accS[mt][r];
    bar_lgkm();
    if (tid < 128)
        stb[DDIM*DDIM + tid] = Zpart[tid] + Zpart[128+tid] + Zpart[256+tid] + Zpart[384+tid];
}

// =====================================================================
// Prefix: in-place exclusive prefix over the 16 chunk states, 1 chain/thread.
__global__ void la_prefix(float* __restrict__ states) {
    const int bh  = blockIdx.y;
    const int idx = blockIdx.x * 128 + threadIdx.x;   // 129*128 = 16512 exact
    float* p = states + (size_t)bh * CHUNKS * STATE_SZ + idx;
    float run = 0.f;
    #pragma unroll
    for (int c = 0; c < CHUNKS; ++c) {
        float v = p[(size_t)c * STATE_SZ];
        p[(size_t)c * STATE_SZ] = run;
        run += v;
    }
}

// =====================================================================
// P2: out = (phi_Q @ S0 + blockcausal(phi_Q @ phi_K^T) @ V) / den
// Wave w owns q-block w (32 rows). phi_Q in registers. 5 barriers total.
// LDS map:
//   [0,32768)        S0T [e=128][d=128] bf16, XOR-swizzled
//   [32768,98304)    kv granule bufs x2: {pk [64][128] bf16 swz | vT [128][64] bf16 swz}
//   [98304,118784)   A scratch, per wave [32 q][40 r] bf16 (2560 B each)
//   [118784,119808)  den [8][32] f32
#define SMEM2 119808
__global__ __launch_bounds__(512, 2) void la_fwd(
    const float* __restrict__ Q, const float* __restrict__ K,
    const float* __restrict__ V, const float* __restrict__ scale,
    const float* __restrict__ bias, const float* __restrict__ states,
    float* __restrict__ out)
{
    extern __shared__ char smem[];
    const int tid  = threadIdx.x;
    const int bh   = blockIdx.x >> 4;
    const int ch   = blockIdx.x & 15;
    const int h    = bh & 15;
    const int lane = tid & 63;
    const int wid  = tid >> 6;      // wave id = q-block id (0..7)
    const int i15  = lane & 15;
    const int q4   = lane >> 4;
    const size_t base = (size_t)bh * LSEQ * DDIM;
    const int row0 = ch * CHUNK_ROWS;
    const float* stb = states + (size_t)(bh*CHUNKS + ch)*STATE_SZ;

    // kv staging assignments
    const int krow = tid >> 3;            // 0..63 (pk row within granule)
    const int kd8  = (tid & 7) * 16;      // pk d-segment
    const int ve   = tid & 127;           // vT row (e)
    const int vrg  = tid >> 7;            // 0..3 -> local r rows 16vrg..16vrg+15

    float skr[16], bkr[16];
    #pragma unroll
    for (int u = 0; u < 4; ++u) {
        *(float4*)&skr[4*u] = *(const float4*)(scale + h*DDIM + kd8 + 4*u);
        *(float4*)&bkr[4*u] = *(const float4*)(bias  + h*DDIM + kd8 + 4*u);
    }

    float4 kq[4];
    float  vr[16];
    auto load_kv = [&](int g) {
        const float* Kr = K + base + (size_t)(row0 + 64*g + krow)*DDIM + kd8;
        #pragma unroll
        for (int u = 0; u < 4; ++u) kq[u] = *(const float4*)(Kr + 4*u);
        const float* Vc = V + base + (size_t)(row0 + 64*g + 16*vrg)*DDIM + ve;
        #pragma unroll
        for (int j = 0; j < 16; ++j) vr[j] = Vc[(size_t)j*DDIM];
    };
    auto stage_kv = [&](int b) {
        char* pkb = smem + 32768 + b*32768;
        char* vtb = pkb + 16384;
        uint32_t wk[8];
        #pragma unroll
        for (int u = 0; u < 4; ++u) {
            float x0 = phi_f(kq[u].x, skr[4*u+0], bkr[4*u+0]);
            float x1 = phi_f(kq[u].y, skr[4*u+1], bkr[4*u+1]);
            float x2 = phi_f(kq[u].z, skr[4*u+2], bkr[4*u+2]);
            float x3 = phi_f(kq[u].w, skr[4*u+3], bkr[4*u+3]);
            wk[2*u]   = pack2(x0, x1);
            wk[2*u+1] = pack2(x2, x3);
        }
        uint32_t lin = (uint32_t)(krow*256 + kd8*2);
        uint32_t swz = (uint32_t)((krow & 7) << 4);
        *(uint4*)(pkb + ((lin     ) ^ swz)) = ((const uint4*)wk)[0];
        *(uint4*)(pkb + ((lin + 16) ^ swz)) = ((const uint4*)wk)[1];
        uint32_t wv8[8];
        #pragma unroll
        for (int j = 0; j < 8; ++j) wv8[j] = pack2(vr[2*j], vr[2*j+1]);
        lin = (uint32_t)(ve*128 + 32*vrg);
        swz = (uint32_t)((ve & 7) << 4);
        *(uint4*)(vtb + ((lin     ) ^ swz)) = ((const uint4*)wv8)[0];
        *(uint4*)(vtb + ((lin + 16) ^ swz)) = ((const uint4*)wv8)[1];
    };

    load_kv(0);

    // ---- stage S0T [e][d] bf16 (strided reads; lines shared via L2 within wg)
    {
        const int se  = tid & 127;
        const int sdg = tid >> 7;            // d range 32sdg..32sdg+31
        float sv[32];
        const float* srcp = stb + (size_t)(32*sdg)*DDIM + se;
        #pragma unroll
        for (int k2 = 0; k2 < 32; ++k2) sv[k2] = srcp[(size_t)k2*DDIM];
        uint32_t wbuf[16];
        #pragma unroll
        for (int k2 = 0; k2 < 16; ++k2) wbuf[k2] = pack2(sv[2*k2], sv[2*k2+1]);
        const uint32_t linb = (uint32_t)(se*256 + 64*sdg);
        const uint32_t swz  = (uint32_t)((se & 7) << 4);
        #pragma unroll
        for (int m = 0; m < 4; ++m)
            *(uint4*)(smem + ((linb + 16*m) ^ swz)) = ((const uint4*)wbuf)[m];
    }

    stage_kv(0);
    load_kv(1);

    // ---- phi_Q fragments in registers + den0 = phi_q . Z0
    bf16x8 pq[2][4];
    float dacc0 = 0.f, dacc1 = 0.f;
    #pragma unroll
    for (int ks = 0; ks < 4; ++ks) {
        const float* sp = scale + h*DDIM + 32*ks + 8*q4;
        const float* bp = bias  + h*DDIM + 32*ks + 8*q4;
        const float* zp = stb + DDIM*DDIM + 32*ks + 8*q4;
        float4 s0 = *(const float4*)sp, s1 = *(const float4*)(sp+4);
        float4 b0 = *(const float4*)bp, b1 = *(const float4*)(bp+4);
        float4 z0 = *(const float4*)zp, z1 = *(const float4*)(zp+4);
        #pragma unroll
        for (int qt = 0; qt < 2; ++qt) {
            const float* qp = Q + base + (size_t)(row0 + 32*wid + 16*qt + i15)*DDIM + 32*ks + 8*q4;
            float4 a0 = *(const float4*)qp, a1 = *(const float4*)(qp+4);
            float f0 = phi_f(a0.x, s0.x, b0.x), f1 = phi_f(a0.y, s0.y, b0.y);
            float f2 = phi_f(a0.z, s0.z, b0.z), f3 = phi_f(a0.w, s0.w, b0.w);
            float f4 = phi_f(a1.x, s1.x, b1.x), f5 = phi_f(a1.y, s1.y, b1.y);
            float f6 = phi_f(a1.z, s1.z, b1.z), f7 = phi_f(a1.w, s1.w, b1.w);
            float ds = f0*z0.x + f1*z0.y + f2*z0.z + f3*z0.w
                     + f4*z1.x + f5*z1.y + f6*z1.z + f7*z1.w;
            if (qt == 0) dacc0 += ds; else dacc1 += ds;
            uint4 uu = { pack2(f0,f1), pack2(f2,f3), pack2(f4,f5), pack2(f6,f7) };
            pq[qt][ks] = __builtin_bit_cast(bf16x8, uu);
        }
    }

    bar_lgkm();   // B0: S0T + kv buf0 visible

    // ---- term1: acc = phi_q @ S0
    f32x4 acc[2][8];
    #pragma unroll
    for (int qt = 0; qt < 2; ++qt)
        #pragma unroll
        for (int et = 0; et < 8; ++et) acc[qt][et] = (f32x4){0.f,0.f,0.f,0.f};
    {
        const uint32_t swz = (uint32_t)((i15 & 7) << 4);
        #pragma unroll
        for (int ks = 0; ks < 4; ++ks)
            #pragma unroll
            for (int et = 0; et < 8; ++et) {
                bf16x8 sb = *(const bf16x8*)(smem + (((uint32_t)((16*et+i15)*256 + 64*ks + 16*q4)) ^ swz));
                acc[0][et] = __builtin_amdgcn_mfma_f32_16x16x32_bf16(pq[0][ks], sb, acc[0][et], 0, 0, 0);
                acc[1][et] = __builtin_amdgcn_mfma_f32_16x16x32_bf16(pq[1][ks], sb, acc[1][et], 0, 0, 0);
            }
    }

    // ---- kv loop: granules of 64 rows (2 kv-blocks), double-buffered
    #pragma unroll
    for (int it = 0; it < 4; ++it) {
        if (it < 3) stage_kv((it+1)&1);
        if (it < 2) load_kv(it+2);
        const char* pkb = smem + 32768 + (it&1)*32768;
        const char* vtb = pkb + 16384;
        const uint32_t swz = (uint32_t)((i15 & 7) << 4);
        #pragma unroll
        for (int tl = 0; tl < 2; ++tl) {
            const int t = 2*it + tl;
            if (t <= wid) {
                f32x4 Aacc[2][2];   // [rt][qt],  A^T: m=r, n=q
                #pragma unroll
                for (int rt = 0; rt < 2; ++rt)
                    #pragma unroll
                    for (int qt = 0; qt < 2; ++qt) Aacc[rt][qt] = (f32x4){0.f,0.f,0.f,0.f};
                #pragma unroll
                for (int ks = 0; ks < 4; ++ks) {
                    bf16x8 ak0 = *(const bf16x8*)(pkb + (((uint32_t)((32*tl      + i15)*256 + 64*ks + 16*q4)) ^ swz));
                    bf16x8 ak1 = *(const bf16x8*)(pkb + (((uint32_t)((32*tl + 16 + i15)*256 + 64*ks + 16*q4)) ^ swz));
                    Aacc[0][0] = __builtin_amdgcn_mfma_f32_16x16x32_bf16(ak0, pq[0][ks], Aacc[0][0], 0, 0, 0);
                    Aacc[0][1] = __builtin_amdgcn_mfma_f32_16x16x32_bf16(ak0, pq[1][ks], Aacc[0][1], 0, 0, 0);
                    Aacc[1][0] = __builtin_amdgcn_mfma_f32_16x16x32_bf16(ak1, pq[0][ks], Aacc[1][0], 0, 0, 0);
                    Aacc[1][1] = __builtin_amdgcn_mfma_f32_16x16x32_bf16(ak1, pq[1][ks], Aacc[1][1], 0, 0, 0);
                }
                // den partials (f32, before bf16 rounding of A)
                dacc0 += Aacc[0][0][0]+Aacc[0][0][1]+Aacc[0][0][2]+Aacc[0][0][3]
                       + Aacc[1][0][0]+Aacc[1][0][1]+Aacc[1][0][2]+Aacc[1][0][3];
                dacc1 += Aacc[0][1][0]+Aacc[0][1][1]+Aacc[0][1][2]+Aacc[0][1][3]
                       + Aacc[1][1][0]+Aacc[1][1][1]+Aacc[1][1][2]+Aacc[1][1][3];
                // emit A[q][r] bf16 to wave-private scratch
                char* al = smem + 98304 + wid*2560;
                #pragma unroll
                for (int rt = 0; rt < 2; ++rt)
                    #pragma unroll
                    for (int qt = 0; qt < 2; ++qt) {
                        uint2 o;
                        o.x = pack2(Aacc[rt][qt][0], Aacc[rt][qt][1]);
                        o.y = pack2(Aacc[rt][qt][2], Aacc[rt][qt][3]);
                        *(uint2*)(al + (uint32_t)(((16*qt + i15)*40 + 16*rt + 4*q4)*2)) = o;
                    }
                bf16x8 aq0 = *(const bf16x8*)(al + (uint32_t)((      i15*40 + 8*q4)*2));
                bf16x8 aq1 = *(const bf16x8*)(al + (uint32_t)(((16 + i15)*40 + 8*q4)*2));
                #pragma unroll
                for (int et = 0; et < 8; ++et) {
                    bf16x8 bvv = *(const bf16x8*)(vtb + (((uint32_t)((16*et+i15)*128 + 64*tl + 16*q4)) ^ swz));
                    acc[0][et] = __builtin_amdgcn_mfma_f32_16x16x32_bf16(aq0, bvv, acc[0][et], 0, 0, 0);
                    acc[1][et] = __builtin_amdgcn_mfma_f32_16x16x32_bf16(aq1, bvv, acc[1][et], 0, 0, 0);
                }
            }
        }
        bar_lgkm();
    }

    // ---- den reduce + normalize + store
    dacc0 += __shfl_xor(dacc0, 16, 64); dacc0 += __shfl_xor(dacc0, 32, 64);
    dacc1 += __shfl_xor(dacc1, 16, 64); dacc1 += __shfl_xor(dacc1, 32, 64);
    float* denl = (float*)(smem + 118784);
    if (q4 == 0) {
        denl[wid*32 + i15]      = dacc0;
        denl[wid*32 + 16 + i15] = dacc1;
    }
    #pragma unroll
    for (int qt = 0; qt < 2; ++qt) {
        float inv[4];
        #pragma unroll
        for (int r = 0; r < 4; ++r)
            inv[r] = 1.0f / fmaxf(denl[wid*32 + 16*qt + 4*q4 + r], 1e-6f);
        #pragma unroll
        for (int et = 0; et < 8; ++et)
            #pragma unroll
            for (int r = 0; r < 4; ++r)
                out[base + (size_t)(row0 + 32*wid + 16*qt + 4*q4 + r)*DDIM + 16*et + i15] =
                    acc[qt][et][r] * inv[r];
    }
}

extern "C" void kernel_launch(void* const* d_in, const int* in_sizes, int n_in,
                              void* d_out, int out_size, void* d_ws, size_t ws_size,
                              hipStream_t stream) {
    const float* Q     = (const float*)d_in[0];
    const float* K     = (const float*)d_in[1];
    const float* V     = (const float*)d_in[2];
    const float* scale = (const float*)d_in[3];
    const float* bias  = (const float*)d_in[4];
    float* out    = (float*)d_out;
    float* states = (float*)d_ws;   // 32*16*16512*4 = 33.8 MB

    static bool s_attr = false;
    if (!s_attr) {
        hipFuncSetAttribute(reinterpret_cast<const void*>(la_state),
                            hipFuncAttributeMaxDynamicSharedMemorySize, SMEM1);
        hipFuncSetAttribute(reinterpret_cast<const void*>(la_fwd),
                            hipFuncAttributeMaxDynamicSharedMemorySize, SMEM2);
        s_attr = true;
    }

    hipLaunchKernelGGL(la_state, dim3(BH*CHUNKS), dim3(512), SMEM1, stream,
                       K, V, scale, bias, states);
    hipLaunchKernelGGL(la_prefix, dim3(129, BH), dim3(128), 0, stream, states);
    hipLaunchKernelGGL(la_fwd, dim3(BH*CHUNKS), dim3(512), SMEM2, stream,
                       Q, K, V, scale, bias, states, out);
}